// Round 7
// baseline (227.864 us; speedup 1.0000x reference)
//
#include <hip/hip_runtime.h>
#include <hip/hip_cooperative_groups.h>
#include <cstddef>

namespace cg = cooperative_groups;

#define NN 100000
#define DD 128
#define ND (NN * DD)
#define BN_EPS 1e-5f
#define LDA 136                // LDS A row stride in bf16 elems (272 B, 16B-aligned)
#define NREP 16                // stats-accumulator replicas
#define NBKT 98                // scatter buckets: 1024 nodes each
#define EPB 4096               // edges per bcnt/k_bin block
#define NT ((NN + 63) / 64)    // 1563 tiles of 64 rows
#define TMAX 4                 // max tiles per persistent block

typedef __bf16 bf16_t;
typedef bf16_t bf16x8 __attribute__((ext_vector_type(8)));
typedef float f32x4 __attribute__((ext_vector_type(4)));
typedef unsigned int uint;
typedef unsigned short ushort;

// ws 4-byte-slot layout:
//   [0, ND/2)            region0: pairs (uint2 x E) pre-k_gg; hb (fallback path)
//   [ND/2, ND)           xb   (bf16 x)
//   base3 = ND:
//   csr[16*128], cqr[16*128], bktot[128], bcur[128]  (memset zeroes all),
//   cnt[NN], ptr0[NN], dinv[NN], srow[E], wb[4096 uints]

__device__ __forceinline__ ushort f2b(float f) {
    uint u = __builtin_bit_cast(uint, f);
    u += 0x7FFFu + ((u >> 16) & 1u);          // RNE
    return (ushort)(u >> 16);
}
__device__ __forceinline__ float b2f(uint s) {
    return __builtin_bit_cast(float, s << 16);
}

// int64 edge_index => high word of every entry is 0 (ids < 100000).
__device__ __forceinline__ int detect_i64(const int* __restrict__ ei) {
    __shared__ int sflag;
    int t = threadIdx.x;
    if (t < 64) {
        int hi = ei[2 * t + 1];
        unsigned long long b = __ballot(hi == 0);
        if (t == 0) sflag = (b == ~0ull) ? 1 : 0;
    }
    __syncthreads();
    return sflag;
}

// dual-role: blocks [0, nbh) LDS-histogram cols into bucket totals;
// rest pack x and W to bf16.
__global__ __launch_bounds__(256) void k_prep(const int* __restrict__ ei,
                                              int* __restrict__ bktot, int E, int nbh,
                                              const float* __restrict__ x,
                                              uint* __restrict__ xb,
                                              const float* __restrict__ W,
                                              uint* __restrict__ wb) {
    if ((int)blockIdx.x < nbh) {
        int f = detect_i64(ei);
        __shared__ int hist[NBKT];
        int t = threadIdx.x;
        if (t < NBKT) hist[t] = 0;
        __syncthreads();
        int base = blockIdx.x * EPB;
        int count = min(EPB, E - base);
        for (int i = t; i < count; i += 256) {
            int e = base + i;
            int c = f ? ei[2 * (E + e)] : ei[E + e];
            atomicAdd(&hist[c >> 10], 1);
        }
        __syncthreads();
        if (t < NBKT && hist[t] > 0) atomicAdd(&bktot[t], hist[t]);
        return;
    }
    int i = (blockIdx.x - nbh) * 256 + threadIdx.x;
    const float* src;
    uint* dst;
    int j;
    if (i < ND / 8) { src = x; dst = xb; j = i; }
    else { j = i - ND / 8; if (j >= (DD * DD) / 8) return; src = W; dst = wb; }
    const float4* s4 = (const float4*)src;
    float4 a = s4[2 * j], b = s4[2 * j + 1];
    uint4 o;
    o.x = (uint)f2b(a.x) | ((uint)f2b(a.y) << 16);
    o.y = (uint)f2b(a.z) | ((uint)f2b(a.w) << 16);
    o.z = (uint)f2b(b.x) | ((uint)f2b(b.y) << 16);
    o.w = (uint)f2b(b.z) | ((uint)f2b(b.w) << 16);
    ((uint4*)dst)[j] = o;
}

// partition edges into NBKT destination buckets.
__global__ __launch_bounds__(256) void k_bin(const int* __restrict__ ei,
                                             const int* __restrict__ bktot,
                                             int* __restrict__ bcur,
                                             uint2* __restrict__ pairs, int E) {
    int f = detect_i64(ei);
    __shared__ int bb[NBKT], hist[NBKT], scur[NBKT];
    int t = threadIdx.x;
    if (t < NBKT) { bb[t] = bktot[t]; hist[t] = 0; }
    __syncthreads();
    if (t == 0) {
        int run = 0;
        for (int i = 0; i < NBKT; ++i) { int v = bb[i]; bb[i] = run; run += v; }
    }
    int base = blockIdx.x * EPB;
    int count = min(EPB, E - base);
    int rr[16], cc[16];
#pragma unroll
    for (int k = 0; k < 16; ++k) {
        int i = t + k * 256;
        if (i < count) {
            int e = base + i;
            int r, c;
            if (f) { r = ei[2 * e]; c = ei[2 * (E + e)]; }
            else   { r = ei[e];     c = ei[E + e]; }
            rr[k] = r; cc[k] = c;
            atomicAdd(&hist[c >> 10], 1);
        }
    }
    __syncthreads();   // joins t0's scan and the histogram
    if (t < NBKT) scur[t] = bb[t] + atomicAdd(&bcur[t], hist[t]);
    __syncthreads();
#pragma unroll
    for (int k = 0; k < 16; ++k) {
        int i = t + k * 256;
        if (i < count) {
            int b = cc[k] >> 10;
            int pos = atomicAdd(&scur[b], 1);
            pairs[pos] = (uint2){(uint)rr[k], (uint)cc[k]};
        }
    }
}

// one block per bucket: LDS histogram + scan -> ptr0/cnt/dinv, scatter srow.
__global__ __launch_bounds__(256) void k_cnt(const uint2* __restrict__ pairs,
                                             const int* __restrict__ bktot,
                                             int* __restrict__ ptr0,
                                             int* __restrict__ cnt,
                                             float* __restrict__ dinv,
                                             int* __restrict__ srow) {
    __shared__ int hist[1024];
    __shared__ int scur[1024];
    __shared__ int ls[256];
    __shared__ int bb[NBKT];
    __shared__ int se0, se1;
    int b = blockIdx.x;
    int t = threadIdx.x;
    if (t < NBKT) bb[t] = bktot[t];
#pragma unroll
    for (int i = 0; i < 4; ++i) hist[t + i * 256] = 0;
    __syncthreads();
    if (t == 0) {
        int run = 0;
        for (int i = 0; i < b; ++i) run += bb[i];
        se0 = run; se1 = run + bb[b];
    }
    __syncthreads();
    int e0 = se0, e1 = se1;
    int nodebase = b << 10;
    for (int i = e0 + t; i < e1; i += 256)
        atomicAdd(&hist[(int)pairs[i].y - nodebase], 1);
    __syncthreads();
    int c4[4];
    int lsum = 0;
#pragma unroll
    for (int i = 0; i < 4; ++i) { c4[i] = hist[t * 4 + i]; lsum += c4[i]; }
    ls[t] = lsum;
    __syncthreads();
    for (int o = 1; o < 256; o <<= 1) {
        int v = (t >= o) ? ls[t - o] : 0;
        __syncthreads();
        ls[t] += v;
        __syncthreads();
    }
    int run = ls[t] - lsum + e0;
#pragma unroll
    for (int i = 0; i < 4; ++i) {
        int idx = nodebase + t * 4 + i;
        if (idx < NN) {
            ptr0[idx] = run;
            cnt[idx] = c4[i];
            dinv[idx] = c4[i] > 0 ? rsqrtf((float)c4[i]) : 0.f;
        }
        scur[t * 4 + i] = run;
        run += c4[i];
    }
    __syncthreads();
    for (int i = e0 + t; i < e1; i += 256) {
        uint2 p = pairs[i];
        int pos = atomicAdd(&scur[(int)p.y - nodebase], 1);
        srow[pos] = (int)p.x;
    }
}

// compute one 64-row tile: gather into sA, MFMA, pack h->bf16 regs (hp!=null)
// or store to hb (hp==null fallback), add stats.
__device__ __forceinline__ void tile_compute(int tile, int wave, int lane,
                                             const uint* __restrict__ xb,
                                             const int* __restrict__ srow,
                                             const int* __restrict__ ptr0,
                                             const int* __restrict__ cnt,
                                             const float* __restrict__ dinv,
                                             const ushort* __restrict__ wb,
                                             float* __restrict__ csr,
                                             float* __restrict__ cqr,
                                             char* smem, uint* hp,
                                             ushort* __restrict__ hb) {
    ushort* sAp = (ushort*)smem;
    int t = wave * 64 + lane;
    uint rowbase = (uint)tile * 64;

    // --- gather: wave handles rows wave*8 .. wave*8+7, 2 at a time ---
    int mn = (int)rowbase + wave * 8 + (lane & 7);
    int sv = 0, kv = 0;
    float dv = 0.f;
    if (lane < 8 && mn < NN) { sv = ptr0[mn]; kv = cnt[mn]; dv = dinv[mn]; }

    for (int i = 0; i < 8; i += 2) {
        int sa0 = __shfl(sv, i),     kA = __shfl(kv, i);
        int sb0 = __shfl(sv, i + 1), kB = __shfl(kv, i + 1);
        float dA = __shfl(dv, i), dB = __shfl(dv, i + 1);
        float axA = 0.f, ayA = 0.f, axB = 0.f, ayB = 0.f;
        int kmax = max(kA, kB);
        for (int base = 0; base < kmax; base += 64) {
            int mA = kA - base; mA = mA > 64 ? 64 : mA;
            int mB = kB - base; mB = mB > 64 ? 64 : mB;
            int rjA = 0, rjB = 0;
            if (lane < mA) rjA = srow[sa0 + base + lane];
            if (lane < mB) rjB = srow[sb0 + base + lane];
            int mm = max(mA, mB);
            for (int j = 0; j < mm; j += 4) {
                int ra0 = __shfl(rjA, j),     rb0 = __shfl(rjB, j);
                int ra1 = __shfl(rjA, j + 1), rb1 = __shfl(rjB, j + 1);
                int ra2 = __shfl(rjA, j + 2), rb2 = __shfl(rjB, j + 2);
                int ra3 = __shfl(rjA, j + 3), rb3 = __shfl(rjB, j + 3);
                uint va0 = xb[((uint)ra0 << 6) + (uint)lane];
                uint vb0 = xb[((uint)rb0 << 6) + (uint)lane];
                uint va1 = xb[((uint)ra1 << 6) + (uint)lane];
                uint vb1 = xb[((uint)rb1 << 6) + (uint)lane];
                uint va2 = xb[((uint)ra2 << 6) + (uint)lane];
                uint vb2 = xb[((uint)rb2 << 6) + (uint)lane];
                uint va3 = xb[((uint)ra3 << 6) + (uint)lane];
                uint vb3 = xb[((uint)rb3 << 6) + (uint)lane];
                float wa0 = dinv[ra0], wbb0 = dinv[rb0];
                float wa1 = dinv[ra1], wbb1 = dinv[rb1];
                float wa2 = dinv[ra2], wbb2 = dinv[rb2];
                float wa3 = dinv[ra3], wbb3 = dinv[rb3];
                wa0 = (j     < mA) ? wa0 : 0.f;  wbb0 = (j     < mB) ? wbb0 : 0.f;
                wa1 = (j + 1 < mA) ? wa1 : 0.f;  wbb1 = (j + 1 < mB) ? wbb1 : 0.f;
                wa2 = (j + 2 < mA) ? wa2 : 0.f;  wbb2 = (j + 2 < mB) ? wbb2 : 0.f;
                wa3 = (j + 3 < mA) ? wa3 : 0.f;  wbb3 = (j + 3 < mB) ? wbb3 : 0.f;
                axA = fmaf(wa0, b2f(va0 & 0xFFFFu), axA); ayA = fmaf(wa0, b2f(va0 >> 16), ayA);
                axA = fmaf(wa1, b2f(va1 & 0xFFFFu), axA); ayA = fmaf(wa1, b2f(va1 >> 16), ayA);
                axA = fmaf(wa2, b2f(va2 & 0xFFFFu), axA); ayA = fmaf(wa2, b2f(va2 >> 16), ayA);
                axA = fmaf(wa3, b2f(va3 & 0xFFFFu), axA); ayA = fmaf(wa3, b2f(va3 >> 16), ayA);
                axB = fmaf(wbb0, b2f(vb0 & 0xFFFFu), axB); ayB = fmaf(wbb0, b2f(vb0 >> 16), ayB);
                axB = fmaf(wbb1, b2f(vb1 & 0xFFFFu), axB); ayB = fmaf(wbb1, b2f(vb1 >> 16), ayB);
                axB = fmaf(wbb2, b2f(vb2 & 0xFFFFu), axB); ayB = fmaf(wbb2, b2f(vb2 >> 16), ayB);
                axB = fmaf(wbb3, b2f(vb3 & 0xFFFFu), axB); ayB = fmaf(wbb3, b2f(vb3 >> 16), ayB);
            }
        }
        *(uint*)(sAp + (wave * 8 + i) * LDA + lane * 2) =
            (uint)f2b(dA * axA) | ((uint)f2b(dA * ayA) << 16);
        *(uint*)(sAp + (wave * 8 + i + 1) * LDA + lane * 2) =
            (uint)f2b(dB * axB) | ((uint)f2b(dB * ayB) << 16);
    }
    __syncthreads();

    // --- GEMM: wave = row-group (wave&3) x ct-half (wave>>2) ---
    int rg = wave & 3, chh = wave >> 2;
    int quad = lane >> 4, l16 = lane & 15;
    bf16x8 Af[4];
#pragma unroll
    for (int ks = 0; ks < 4; ++ks)
        Af[ks] = __builtin_bit_cast(
            bf16x8, *(const uint4*)(sAp + (rg * 16 + l16) * LDA + ks * 32 + quad * 8));
    __syncthreads();                           // sA dead; reuse its LDS for cp/cq
    float (*cp)[64] = (float (*)[64])smem;
    float (*cq)[64] = (float (*)[64])(smem + 8 * 64 * 4);

#pragma unroll
    for (int c = 0; c < 4; ++c) {
        int ctg = chh * 4 + c;
        bf16x8 Bf[4];
#pragma unroll
        for (int ks = 0; ks < 4; ++ks)
            Bf[ks] = __builtin_bit_cast(
                bf16x8,
                *(const uint4*)(wb + (uint)(ctg * 16 + l16) * 128 + ks * 32 + quad * 8));
        f32x4 acc = (f32x4){0.f, 0.f, 0.f, 0.f};
#pragma unroll
        for (int ks = 0; ks < 4; ++ks)
            acc = __builtin_amdgcn_mfma_f32_16x16x32_bf16(Af[ks], Bf[ks], acc, 0, 0, 0);
        float ss = 0.f, qq = 0.f;
#pragma unroll
        for (int r = 0; r < 4; ++r) { float v = acc[r]; ss += v; qq += v * v; }
        if (hp) {
            hp[c * 2]     = (uint)f2b(acc[0]) | ((uint)f2b(acc[1]) << 16);
            hp[c * 2 + 1] = (uint)f2b(acc[2]) | ((uint)f2b(acc[3]) << 16);
        } else {
#pragma unroll
            for (int r = 0; r < 4; ++r) {
                uint row = rowbase + rg * 16 + quad * 4 + r;
                if (row < NN) hb[row * 128u + (uint)(ctg * 16 + l16)] = f2b(acc[r]);
            }
        }
        ss += __shfl_xor(ss, 16); ss += __shfl_xor(ss, 32);
        qq += __shfl_xor(qq, 16); qq += __shfl_xor(qq, 32);
        if (quad == 0) { cp[wave][c * 16 + l16] = ss; cq[wave][c * 16 + l16] = qq; }
    }
    __syncthreads();
    if (t < 128) {
        int w0 = (t >> 6) * 4, lc = t & 63;
        float s = cp[w0][lc] + cp[w0 + 1][lc] + cp[w0 + 2][lc] + cp[w0 + 3][lc];
        float q = cq[w0][lc] + cq[w0 + 1][lc] + cq[w0 + 2][lc] + cq[w0 + 3][lc];
        int rep = (tile & (NREP - 1)) * 128 + t;
        atomicAdd(&csr[rep], s);
        atomicAdd(&cqr[rep], q);
    }
    __syncthreads();                           // LDS reusable by next tile
}

// apply BN+relu+residual for one held tile from packed regs.
__device__ __forceinline__ void tile_epilogue(int tile, int wave, int lane,
                                              const ushort* __restrict__ xbs,
                                              const float* sa, const float* sb,
                                              float* __restrict__ out,
                                              const uint hp[8]) {
    uint rowbase = (uint)tile * 64;
    int rg = wave & 3, chh = wave >> 2;
    int quad = lane >> 4, l16 = lane & 15;
#pragma unroll
    for (int c = 0; c < 4; ++c) {
        int col = chh * 64 + c * 16 + l16;
        float A = sa[col], B = sb[col];
#pragma unroll
        for (int r = 0; r < 4; ++r) {
            uint row = rowbase + rg * 16 + quad * 4 + r;
            if (row < NN) {
                float h = b2f((hp[c * 2 + (r >> 1)] >> ((r & 1) * 16)) & 0xFFFFu);
                float xv = b2f((uint)xbs[row * 128u + (uint)col]);
                out[row * 128u + (uint)col] = fmaxf(fmaf(h, A, B), 0.f) + xv;
            }
        }
    }
}

// FUSED persistent cooperative kernel: up to TMAX tiles/block, h held packed
// bf16 in registers across the grid sync; grid sized by occupancy query.
__global__ __launch_bounds__(512, 4) void k_ggf(const uint* __restrict__ xb,
                                                const int* __restrict__ srow,
                                                const int* __restrict__ ptr0,
                                                const int* __restrict__ cnt,
                                                const float* __restrict__ dinv,
                                                const ushort* __restrict__ wb,
                                                float* __restrict__ csr,
                                                float* __restrict__ cqr,
                                                const float* __restrict__ gamma,
                                                const float* __restrict__ beta,
                                                float* __restrict__ out, int out_size) {
    __shared__ char smem[64 * LDA * 2];       // 17.4 KB scratch (sA / cp,cq / sa,sb)
    int t = threadIdx.x;
    int wave = t >> 6, lane = t & 63;
    int bid = blockIdx.x, g = gridDim.x;

    uint hp[TMAX][8];
#pragma unroll
    for (int i = 0; i < TMAX; ++i) {
        int tile = bid + i * g;
        if (tile < NT)
            tile_compute(tile, wave, lane, xb, srow, ptr0, cnt, dinv, wb, csr, cqr,
                         smem, hp[i], nullptr);
    }

    __threadfence();
    cg::this_grid().sync();

    // fold stat replicas -> BN coefs in LDS (agent-scope coherent loads)
    float* sa = (float*)smem;
    float* sb = sa + 128;
    const float invN = 1.0f / NN;
    if (t < 128) {
        float s = 0.f;
        for (int i = 0; i < NREP; ++i)
            s += __hip_atomic_load(&csr[i * 128 + t], __ATOMIC_RELAXED,
                                   __HIP_MEMORY_SCOPE_AGENT);
        float q = 0.f;
        for (int i = 0; i < NREP; ++i)
            q += __hip_atomic_load(&cqr[i * 128 + t], __ATOMIC_RELAXED,
                                   __HIP_MEMORY_SCOPE_AGENT);
        float m = s * invN;
        float var = q * invN - m * m;
        float inv = rsqrtf(var + BN_EPS);
        float A = inv * gamma[t];
        sa[t] = A;
        sb[t] = beta[t] - m * A;
    }
    __syncthreads();

    const ushort* xbs = (const ushort*)xb;
#pragma unroll
    for (int i = 0; i < TMAX; ++i) {
        int tile = bid + i * g;
        if (tile < NT)
            tile_epilogue(tile, wave, lane, xbs, sa, sb, out, hp[i]);
    }
    if (bid == 0 && t == 0 && out_size > ND) out[ND] = 0.0f;
}

// ---- fallback path (R5 split, proven): gg writes hb; k_final applies BN ----
__global__ __launch_bounds__(512, 4) void k_gg(const uint* __restrict__ xb,
                                               const int* __restrict__ srow,
                                               const int* __restrict__ ptr0,
                                               const int* __restrict__ cnt,
                                               const float* __restrict__ dinv,
                                               const ushort* __restrict__ wb,
                                               ushort* __restrict__ hb,
                                               float* __restrict__ csr,
                                               float* __restrict__ cqr) {
    __shared__ char smem[64 * LDA * 2];
    int t = threadIdx.x;
    tile_compute(blockIdx.x, t >> 6, t & 63, xb, srow, ptr0, cnt, dinv, wb, csr, cqr,
                 smem, nullptr, hb);
}

__global__ __launch_bounds__(256) void k_final(const uint* __restrict__ hb,
                                               const uint* __restrict__ xb,
                                               const float* __restrict__ gamma,
                                               const float* __restrict__ beta,
                                               const float* __restrict__ csr,
                                               const float* __restrict__ cqr,
                                               float* __restrict__ out, int out_size) {
    __shared__ float sa[128], sb[128];
    int t = threadIdx.x;
    const float invN = 1.0f / NN;
    if (t < 128) {
        float s = 0.f;
        for (int i = 0; i < NREP; ++i) s += csr[i * 128 + t];
        sa[t] = s * invN;
    } else {
        int c = t - 128;
        float s = 0.f;
        for (int i = 0; i < NREP; ++i) s += cqr[i * 128 + c];
        sb[c] = s * invN;
    }
    __syncthreads();
    if (t < 128) {
        float m = sa[t];
        float var = sb[t] - m * m;
        float inv = rsqrtf(var + BN_EPS);
        float A = inv * gamma[t];
        float B = beta[t] - m * A;
        sa[t] = A; sb[t] = B;
    }
    __syncthreads();

    int c0 = (t & 7) * 16;
    int u8 = blockIdx.x * 512 + t * 2;
    uint4 hv0 = ((const uint4*)hb)[u8], hv1 = ((const uint4*)hb)[u8 + 1];
    uint4 xv0 = ((const uint4*)xb)[u8], xv1 = ((const uint4*)xb)[u8 + 1];
    uint hu[8] = {hv0.x, hv0.y, hv0.z, hv0.w, hv1.x, hv1.y, hv1.z, hv1.w};
    uint xu[8] = {xv0.x, xv0.y, xv0.z, xv0.w, xv1.x, xv1.y, xv1.z, xv1.w};
    float res[16];
#pragma unroll
    for (int p = 0; p < 8; ++p) {
        int c = c0 + p * 2;
        float h0 = b2f(hu[p] & 0xFFFFu), h1 = b2f(hu[p] >> 16);
        float x0 = b2f(xu[p] & 0xFFFFu), x1 = b2f(xu[p] >> 16);
        res[2 * p]     = fmaxf(fmaf(h0, sa[c],     sb[c]),     0.f) + x0;
        res[2 * p + 1] = fmaxf(fmaf(h1, sa[c + 1], sb[c + 1]), 0.f) + x1;
    }
    float4* o4 = (float4*)out;
    int ob = blockIdx.x * 1024 + t * 4;
#pragma unroll
    for (int q = 0; q < 4; ++q)
        o4[ob + q] = (float4){res[4 * q], res[4 * q + 1], res[4 * q + 2], res[4 * q + 3]};
    if (blockIdx.x == 0 && t == 0 && out_size > ND) out[ND] = 0.0f;
}

extern "C" void kernel_launch(void* const* d_in, const int* in_sizes, int n_in,
                              void* d_out, int out_size, void* d_ws, size_t ws_size,
                              hipStream_t stream) {
    const float* x     = (const float*)d_in[0];
    const int*   ei    = (const int*)d_in[1];
    const float* W     = (const float*)d_in[2];
    const float* gamma = (const float*)d_in[4];
    const float* beta  = (const float*)d_in[5];
    float* ws = (float*)d_ws;
    float* out = (float*)d_out;

    uint*   region0  = (uint*)ws;                      // pairs, then hb (fallback)
    uint*   xb       = region0 + ND / 2;
    float*  csr      = (float*)(xb + ND / 2);          // 16*128
    float*  cqr      = csr + NREP * 128;               // 16*128
    int*    bktot    = (int*)(cqr + NREP * 128);       // 128 (zeroed)
    int*    bcur     = bktot + 128;                    // 128 (zeroed)
    int*    cnt      = bcur + 128;                     // NN
    int*    ptr0     = cnt + NN;                       // NN
    float*  dinv     = (float*)(ptr0 + NN);            // NN
    int*    srow     = (int*)(dinv + NN);              // E

    int E = in_sizes[1] / 2;
    uint* wb = (uint*)(srow + E);
    uint2* pairs = (uint2*)region0;

    int nbc = (ND / 8 + (DD * DD) / 8 + 255) / 256;
    int nbin = (E + EPB - 1) / EPB;

    hipMemsetAsync(csr, 0, (size_t)(2 * NREP * 128 + 256) * 4, stream);
    k_prep<<<nbin + nbc, 256, 0, stream>>>(ei, bktot, E, nbin, x, xb, W, wb);
    k_bin<<<nbin, 256, 0, stream>>>(ei, bktot, bcur, pairs, E);
    k_cnt<<<NBKT, 256, 0, stream>>>(pairs, bktot, ptr0, cnt, dinv, srow);

    // cooperative grid sized by what actually fits (VGPR/LDS-aware)
    static int coopGrid = -2;
    if (coopGrid == -2) {
        int nb = 0;
        if (hipOccupancyMaxActiveBlocksPerMultiprocessor(&nb, (const void*)k_ggf,
                                                         512, 0) != hipSuccess)
            nb = 0;
        long g = (long)nb * 256;
        if (g > 1024) g = 1024;
        coopGrid = (g > 0 && g * TMAX >= NT) ? (int)g : 0;
    }

    bool done = false;
    if (coopGrid > 0) {
        const uint*   a_xb   = xb;
        const int*    a_srow = srow;
        const int*    a_ptr0 = ptr0;
        const int*    a_cnt  = cnt;
        const float*  a_dinv = dinv;
        const ushort* a_wb   = (const ushort*)wb;
        float*        a_csr  = csr;
        float*        a_cqr  = cqr;
        const float*  a_g    = gamma;
        const float*  a_b    = beta;
        float*        a_out  = out;
        int           a_os   = out_size;
        void* args[] = {(void*)&a_xb, (void*)&a_srow, (void*)&a_ptr0, (void*)&a_cnt,
                        (void*)&a_dinv, (void*)&a_wb, (void*)&a_csr, (void*)&a_cqr,
                        (void*)&a_g, (void*)&a_b, (void*)&a_out, (void*)&a_os};
        hipError_t err = hipLaunchCooperativeKernel((void*)k_ggf, dim3(coopGrid),
                                                    dim3(512), args, 0, stream);
        if (err == hipSuccess) done = true;
        else coopGrid = 0;                      // remember failure
    }
    if (!done) {
        // fallback: split path (hb aliases region0; pairs dead after k_cnt)
        k_gg<<<NT, 512, 0, stream>>>(xb, srow, ptr0, cnt, dinv, (const ushort*)wb,
                                     (ushort*)region0, csr, cqr);
        k_final<<<ND / 4096, 256, 0, stream>>>(region0, xb, gamma, beta, csr, cqr,
                                               out, out_size);
    }
}

// Round 8
// 223.965 us; speedup vs baseline: 1.0174x; 1.0174x over previous
//
#include <hip/hip_runtime.h>
#include <cstddef>

#define NN 100000
#define DD 128
#define ND (NN * DD)
#define BN_EPS 1e-5f
#define LDA 136                // LDS A row stride in bf16 elems (272 B, 16B-aligned)
#define NREP 16                // stats-accumulator replicas
#define NBKT 98                // scatter buckets: 1024 nodes each
#define EPB 4096               // edges per bcnt/k_bin block
#define NT ((NN + 63) / 64)    // 1563 tiles of 64 rows

typedef __bf16 bf16_t;
typedef bf16_t bf16x8 __attribute__((ext_vector_type(8)));
typedef float f32x4 __attribute__((ext_vector_type(4)));
typedef unsigned int uint;
typedef unsigned short ushort;

// ws 4-byte-slot layout:
//   [0, ND/2)            region0: pairs (uint2 x E) pre-gg; hb after
//   [ND/2, ND)           xb   (bf16 x)
//   base3 = ND:
//   csr[16*128], cqr[16*128], bktot[128], bcur[128]  (memset zeroes all),
//   cnt[NN], ptr0[NN], dinv[NN], srow[E], wb[4096 uints]

__device__ __forceinline__ ushort f2b(float f) {
    uint u = __builtin_bit_cast(uint, f);
    u += 0x7FFFu + ((u >> 16) & 1u);          // RNE
    return (ushort)(u >> 16);
}
__device__ __forceinline__ float b2f(uint s) {
    return __builtin_bit_cast(float, s << 16);
}
__device__ __forceinline__ float blo(uint u) {          // low bf16 -> f32
    return __builtin_bit_cast(float, u << 16);
}
__device__ __forceinline__ float bhi(uint u) {          // high bf16 -> f32
    return __builtin_bit_cast(float, u & 0xFFFF0000u);
}

// int64 edge_index => high word of every entry is 0 (ids < 100000).
__device__ __forceinline__ int detect_i64(const int* __restrict__ ei) {
    __shared__ int sflag;
    int t = threadIdx.x;
    if (t < 64) {
        int hi = ei[2 * t + 1];
        unsigned long long b = __ballot(hi == 0);
        if (t == 0) sflag = (b == ~0ull) ? 1 : 0;
    }
    __syncthreads();
    return sflag;
}

// dual-role: blocks [0, nbh) LDS-histogram cols into bucket totals;
// rest pack x and W to bf16.
__global__ __launch_bounds__(256) void k_prep(const int* __restrict__ ei,
                                              int* __restrict__ bktot, int E, int nbh,
                                              const float* __restrict__ x,
                                              uint* __restrict__ xb,
                                              const float* __restrict__ W,
                                              uint* __restrict__ wb) {
    if ((int)blockIdx.x < nbh) {
        int f = detect_i64(ei);
        __shared__ int hist[NBKT];
        int t = threadIdx.x;
        if (t < NBKT) hist[t] = 0;
        __syncthreads();
        int base = blockIdx.x * EPB;
        int count = min(EPB, E - base);
        for (int i = t; i < count; i += 256) {
            int e = base + i;
            int c = f ? ei[2 * (E + e)] : ei[E + e];
            atomicAdd(&hist[c >> 10], 1);
        }
        __syncthreads();
        if (t < NBKT && hist[t] > 0) atomicAdd(&bktot[t], hist[t]);
        return;
    }
    int i = (blockIdx.x - nbh) * 256 + threadIdx.x;
    const float* src;
    uint* dst;
    int j;
    if (i < ND / 8) { src = x; dst = xb; j = i; }
    else { j = i - ND / 8; if (j >= (DD * DD) / 8) return; src = W; dst = wb; }
    const float4* s4 = (const float4*)src;
    float4 a = s4[2 * j], b = s4[2 * j + 1];
    uint4 o;
    o.x = (uint)f2b(a.x) | ((uint)f2b(a.y) << 16);
    o.y = (uint)f2b(a.z) | ((uint)f2b(a.w) << 16);
    o.z = (uint)f2b(b.x) | ((uint)f2b(b.y) << 16);
    o.w = (uint)f2b(b.z) | ((uint)f2b(b.w) << 16);
    ((uint4*)dst)[j] = o;
}

// partition edges into NBKT destination buckets.
__global__ __launch_bounds__(256) void k_bin(const int* __restrict__ ei,
                                             const int* __restrict__ bktot,
                                             int* __restrict__ bcur,
                                             uint2* __restrict__ pairs, int E) {
    int f = detect_i64(ei);
    __shared__ int bb[NBKT], hist[NBKT], scur[NBKT];
    int t = threadIdx.x;
    if (t < NBKT) { bb[t] = bktot[t]; hist[t] = 0; }
    __syncthreads();
    if (t == 0) {
        int run = 0;
        for (int i = 0; i < NBKT; ++i) { int v = bb[i]; bb[i] = run; run += v; }
    }
    int base = blockIdx.x * EPB;
    int count = min(EPB, E - base);
    int rr[16], cc[16];
#pragma unroll
    for (int k = 0; k < 16; ++k) {
        int i = t + k * 256;
        if (i < count) {
            int e = base + i;
            int r, c;
            if (f) { r = ei[2 * e]; c = ei[2 * (E + e)]; }
            else   { r = ei[e];     c = ei[E + e]; }
            rr[k] = r; cc[k] = c;
            atomicAdd(&hist[c >> 10], 1);
        }
    }
    __syncthreads();   // joins t0's scan and the histogram
    if (t < NBKT) scur[t] = bb[t] + atomicAdd(&bcur[t], hist[t]);
    __syncthreads();
#pragma unroll
    for (int k = 0; k < 16; ++k) {
        int i = t + k * 256;
        if (i < count) {
            int b = cc[k] >> 10;
            int pos = atomicAdd(&scur[b], 1);
            pairs[pos] = (uint2){(uint)rr[k], (uint)cc[k]};
        }
    }
}

// one block per bucket: LDS histogram + scan -> ptr0/cnt/dinv, scatter srow.
__global__ __launch_bounds__(256) void k_cnt(const uint2* __restrict__ pairs,
                                             const int* __restrict__ bktot,
                                             int* __restrict__ ptr0,
                                             int* __restrict__ cnt,
                                             float* __restrict__ dinv,
                                             int* __restrict__ srow) {
    __shared__ int hist[1024];
    __shared__ int scur[1024];
    __shared__ int ls[256];
    __shared__ int bb[NBKT];
    __shared__ int se0, se1;
    int b = blockIdx.x;
    int t = threadIdx.x;
    if (t < NBKT) bb[t] = bktot[t];
#pragma unroll
    for (int i = 0; i < 4; ++i) hist[t + i * 256] = 0;
    __syncthreads();
    if (t == 0) {
        int run = 0;
        for (int i = 0; i < b; ++i) run += bb[i];
        se0 = run; se1 = run + bb[b];
    }
    __syncthreads();
    int e0 = se0, e1 = se1;
    int nodebase = b << 10;
    for (int i = e0 + t; i < e1; i += 256)
        atomicAdd(&hist[(int)pairs[i].y - nodebase], 1);
    __syncthreads();
    int c4[4];
    int lsum = 0;
#pragma unroll
    for (int i = 0; i < 4; ++i) { c4[i] = hist[t * 4 + i]; lsum += c4[i]; }
    ls[t] = lsum;
    __syncthreads();
    for (int o = 1; o < 256; o <<= 1) {
        int v = (t >= o) ? ls[t - o] : 0;
        __syncthreads();
        ls[t] += v;
        __syncthreads();
    }
    int run = ls[t] - lsum + e0;
#pragma unroll
    for (int i = 0; i < 4; ++i) {
        int idx = nodebase + t * 4 + i;
        if (idx < NN) {
            ptr0[idx] = run;
            cnt[idx] = c4[i];
            dinv[idx] = c4[i] > 0 ? rsqrtf((float)c4[i]) : 0.f;
        }
        scur[t * 4 + i] = run;
        run += c4[i];
    }
    __syncthreads();
    for (int i = e0 + t; i < e1; i += 256) {
        uint2 p = pairs[i];
        int pos = atomicAdd(&scur[(int)p.y - nodebase], 1);
        srow[pos] = (int)p.x;
    }
}

// FUSED gather + GEMM + stats. Block = 8 waves = 512 thr, 64-row tile.
// Gather: quad-per-node — 4 nodes/wave at a time, 16 lanes each; one uint4
// load instr fetches 4 source rows (1 KB); dinv is a quad-uniform load
// (4 addrs/instr); edge broadcast via per-lane-indexed shfl. ~0.3 VMEM
// instr/edge vs ~2.1 in the 2-way scheme.
__global__ __launch_bounds__(512, 4) void k_gg(const uint* __restrict__ xb,
                                               const int* __restrict__ srow,
                                               const int* __restrict__ ptr0,
                                               const int* __restrict__ cnt,
                                               const float* __restrict__ dinv,
                                               const ushort* __restrict__ wb,
                                               ushort* __restrict__ hb,
                                               float* __restrict__ csr,
                                               float* __restrict__ cqr) {
    __shared__ ushort sA[64 * LDA];            // 17.4 KB
    __shared__ float cp[8][64], cq[8][64];     // 4 KB
    int t = threadIdx.x;
    int wave = t >> 6, lane = t & 63;
    int quad = lane >> 4, l16 = lane & 15;
    uint rowbase = (uint)blockIdx.x * 64;
    const uint4* xb4 = (const uint4*)xb;

    // wave owns rows wave*8 .. wave*8+7; lanes 0..7 hold per-node meta
    int mn = (int)rowbase + wave * 8 + (lane & 7);
    int sv = 0, kv = 0;
    float dv = 0.f;
    if (lane < 8 && mn < NN) { sv = ptr0[mn]; kv = cnt[mn]; dv = dinv[mn]; }

    for (int bt = 0; bt < 2; ++bt) {           // 2 batches of 4 nodes
        int ni = bt * 4 + quad;                // this quad's node (0..7)
        int s_here = __shfl(sv, ni);
        int k_here = __shfl(kv, ni);
        float d_here = __shfl(dv, ni);
        int km = max(k_here, __shfl_xor(k_here, 16));
        km = max(km, __shfl_xor(km, 32));      // max degree over the 4 quads

        float ax0 = 0.f, ax1 = 0.f, ax2 = 0.f, ax3 = 0.f;
        float ax4 = 0.f, ax5 = 0.f, ax6 = 0.f, ax7 = 0.f;

        for (int base = 0; base < km; base += 16) {
            int rem = k_here - base;           // quad-uniform
            int rj = 0;
            if (l16 < rem) rj = srow[s_here + base + l16];
            int jend = km - base; jend = jend > 16 ? 16 : jend;
            for (int j = 0; j < jend; j += 4) {
#pragma unroll
                for (int u = 0; u < 4; ++u) {
                    int jj = j + u;            // jj < 16 always (jend<=16, j<=12)
                    int rsel = __shfl(rj, (lane & 48) + jj);
                    float w = dinv[rsel];      // quad-uniform load
                    uint4 v = xb4[((uint)rsel << 4) + (uint)l16];
                    w = (jj < rem) ? w : 0.f;  // tail mask (rsel=0 row is safe)
                    ax0 = fmaf(w, blo(v.x), ax0); ax1 = fmaf(w, bhi(v.x), ax1);
                    ax2 = fmaf(w, blo(v.y), ax2); ax3 = fmaf(w, bhi(v.y), ax3);
                    ax4 = fmaf(w, blo(v.z), ax4); ax5 = fmaf(w, bhi(v.z), ax5);
                    ax6 = fmaf(w, blo(v.w), ax6); ax7 = fmaf(w, bhi(v.w), ax7);
                }
            }
        }
        uint4 o;
        o.x = (uint)f2b(d_here * ax0) | ((uint)f2b(d_here * ax1) << 16);
        o.y = (uint)f2b(d_here * ax2) | ((uint)f2b(d_here * ax3) << 16);
        o.z = (uint)f2b(d_here * ax4) | ((uint)f2b(d_here * ax5) << 16);
        o.w = (uint)f2b(d_here * ax6) | ((uint)f2b(d_here * ax7) << 16);
        *(uint4*)(sA + (wave * 8 + ni) * LDA + l16 * 8) = o;   // zeros for OOB
    }
    __syncthreads();

    // --- GEMM: wave = row-group (wave&3) x ct-half (wave>>2) ---
    int rg = wave & 3, chh = wave >> 2;
    bf16x8 Af[4];
#pragma unroll
    for (int ks = 0; ks < 4; ++ks)
        Af[ks] = __builtin_bit_cast(
            bf16x8, *(const uint4*)(sA + (rg * 16 + l16) * LDA + ks * 32 + quad * 8));

#pragma unroll
    for (int c = 0; c < 4; ++c) {
        int ctg = chh * 4 + c;
        bf16x8 Bf[4];
#pragma unroll
        for (int ks = 0; ks < 4; ++ks)
            Bf[ks] = __builtin_bit_cast(
                bf16x8,
                *(const uint4*)(wb + (uint)(ctg * 16 + l16) * 128 + ks * 32 + quad * 8));
        f32x4 acc = (f32x4){0.f, 0.f, 0.f, 0.f};
#pragma unroll
        for (int ks = 0; ks < 4; ++ks)
            acc = __builtin_amdgcn_mfma_f32_16x16x32_bf16(Af[ks], Bf[ks], acc, 0, 0, 0);
        float ss = 0.f, qq = 0.f;
#pragma unroll
        for (int r = 0; r < 4; ++r) {
            float v = acc[r];
            ss += v; qq += v * v;
            uint row = rowbase + rg * 16 + quad * 4 + r;
            if (row < NN) hb[row * 128u + (uint)(ctg * 16 + l16)] = f2b(v);
        }
        ss += __shfl_xor(ss, 16); ss += __shfl_xor(ss, 32);
        qq += __shfl_xor(qq, 16); qq += __shfl_xor(qq, 32);
        if (quad == 0) { cp[wave][c * 16 + l16] = ss; cq[wave][c * 16 + l16] = qq; }
    }
    __syncthreads();
    if (t < 128) {
        int w0 = (t >> 6) * 4, lc = t & 63;
        float s = cp[w0][lc] + cp[w0 + 1][lc] + cp[w0 + 2][lc] + cp[w0 + 3][lc];
        float q = cq[w0][lc] + cq[w0 + 1][lc] + cq[w0 + 2][lc] + cq[w0 + 3][lc];
        int rep = ((int)blockIdx.x & (NREP - 1)) * 128 + t;
        atomicAdd(&csr[rep], s);
        atomicAdd(&cqr[rep], q);
    }
}

// BN + relu + residual; folds the NREP stat replicas in LDS.
__global__ __launch_bounds__(256) void k_final(const uint* __restrict__ hb,
                                               const uint* __restrict__ xb,
                                               const float* __restrict__ gamma,
                                               const float* __restrict__ beta,
                                               const float* __restrict__ csr,
                                               const float* __restrict__ cqr,
                                               float* __restrict__ out, int out_size) {
    __shared__ float sa[128], sb[128];
    int t = threadIdx.x;
    const float invN = 1.0f / NN;
    if (t < 128) {
        float s = 0.f;
        for (int i = 0; i < NREP; ++i) s += csr[i * 128 + t];
        sa[t] = s * invN;
    } else {
        int c = t - 128;
        float s = 0.f;
        for (int i = 0; i < NREP; ++i) s += cqr[i * 128 + c];
        sb[c] = s * invN;
    }
    __syncthreads();
    if (t < 128) {
        float m = sa[t];
        float var = sb[t] - m * m;
        float inv = rsqrtf(var + BN_EPS);
        float A = inv * gamma[t];
        float B = beta[t] - m * A;
        sa[t] = A; sb[t] = B;
    }
    __syncthreads();

    int c0 = (t & 7) * 16;
    int u8 = blockIdx.x * 512 + t * 2;
    uint4 hv0 = ((const uint4*)hb)[u8], hv1 = ((const uint4*)hb)[u8 + 1];
    uint4 xv0 = ((const uint4*)xb)[u8], xv1 = ((const uint4*)xb)[u8 + 1];
    uint hu[8] = {hv0.x, hv0.y, hv0.z, hv0.w, hv1.x, hv1.y, hv1.z, hv1.w};
    uint xu[8] = {xv0.x, xv0.y, xv0.z, xv0.w, xv1.x, xv1.y, xv1.z, xv1.w};
    float res[16];
#pragma unroll
    for (int p = 0; p < 8; ++p) {
        int c = c0 + p * 2;
        float h0 = blo(hu[p]), h1 = bhi(hu[p]);
        float x0 = blo(xu[p]), x1 = bhi(xu[p]);
        res[2 * p]     = fmaxf(fmaf(h0, sa[c],     sb[c]),     0.f) + x0;
        res[2 * p + 1] = fmaxf(fmaf(h1, sa[c + 1], sb[c + 1]), 0.f) + x1;
    }
    float4* o4 = (float4*)out;
    int ob = blockIdx.x * 1024 + t * 4;
#pragma unroll
    for (int q = 0; q < 4; ++q)
        o4[ob + q] = (float4){res[4 * q], res[4 * q + 1], res[4 * q + 2], res[4 * q + 3]};
    if (blockIdx.x == 0 && t == 0 && out_size > ND) out[ND] = 0.0f;
}

extern "C" void kernel_launch(void* const* d_in, const int* in_sizes, int n_in,
                              void* d_out, int out_size, void* d_ws, size_t ws_size,
                              hipStream_t stream) {
    const float* x     = (const float*)d_in[0];
    const int*   ei    = (const int*)d_in[1];
    const float* W     = (const float*)d_in[2];
    const float* gamma = (const float*)d_in[4];
    const float* beta  = (const float*)d_in[5];
    float* ws = (float*)d_ws;
    float* out = (float*)d_out;

    uint*   region0  = (uint*)ws;                      // pairs, then hb
    uint*   xb       = region0 + ND / 2;
    float*  csr      = (float*)(xb + ND / 2);          // 16*128
    float*  cqr      = csr + NREP * 128;               // 16*128
    int*    bktot    = (int*)(cqr + NREP * 128);       // 128 (zeroed)
    int*    bcur     = bktot + 128;                    // 128 (zeroed)
    int*    cnt      = bcur + 128;                     // NN
    int*    ptr0     = cnt + NN;                       // NN
    float*  dinv     = (float*)(ptr0 + NN);            // NN
    int*    srow     = (int*)(dinv + NN);              // E

    int E = in_sizes[1] / 2;
    uint* wb = (uint*)(srow + E);
    uint2* pairs = (uint2*)region0;

    int nbc = (ND / 8 + (DD * DD) / 8 + 255) / 256;
    int nbin = (E + EPB - 1) / EPB;

    hipMemsetAsync(csr, 0, (size_t)(2 * NREP * 128 + 256) * 4, stream);
    k_prep<<<nbin + nbc, 256, 0, stream>>>(ei, bktot, E, nbin, x, xb, W, wb);
    k_bin<<<nbin, 256, 0, stream>>>(ei, bktot, bcur, pairs, E);
    k_cnt<<<NBKT, 256, 0, stream>>>(pairs, bktot, ptr0, cnt, dinv, srow);
    k_gg<<<NT, 512, 0, stream>>>(xb, srow, ptr0, cnt, dinv, (const ushort*)wb,
                                 (ushort*)region0, csr, cqr);
    k_final<<<ND / 4096, 256, 0, stream>>>(region0, xb, gamma, beta, csr, cqr,
                                           out, out_size);
}